// Round 3
// baseline (119.340 us; speedup 1.0000x reference)
//
#include <hip/hip_runtime.h>
#include <math.h>

#define NCH   64
#define IMW   512
#define NPTS  150000
#define TOTAL (2 * NPTS)
#define IMHW  (512 * 512)
#define HID   32
#define NBINS 32768   // 2 batches x 512 y x 32 x-cells (16 px = one 64B line)

// ---------- sort pass ----------

__global__ __launch_bounds__(256) void hist_kernel(const int* __restrict__ coords,
                                                   int* __restrict__ hist) {
    int gid = blockIdx.x * blockDim.x + threadIdx.x;
    if (gid >= TOTAL) return;
    const int y = coords[gid * 3 + 1];
    const int x = coords[gid * 3 + 2];
    const int b = (gid >= NPTS) ? 1 : 0;
    const int key = (b << 14) | (y << 5) | (x >> 4);
    atomicAdd(&hist[key], 1);
}

// single-block exclusive scan of 32768 ints (1024 thr x 32 each)
__global__ __launch_bounds__(1024) void scan_kernel(const int* __restrict__ hist,
                                                    int* __restrict__ binPos) {
    __shared__ int lds[1024];
    const int t = threadIdx.x;
    const int base = t * 32;
    int loc[32];
    int s = 0;
    #pragma unroll
    for (int i = 0; i < 32; ++i) { loc[i] = s; s += hist[base + i]; }
    lds[t] = s;
    __syncthreads();
    for (int d = 1; d < 1024; d <<= 1) {
        int v = lds[t];
        int add = (t >= d) ? lds[t - d] : 0;
        __syncthreads();
        lds[t] = v + add;
        __syncthreads();
    }
    const int excl = lds[t] - s;
    #pragma unroll
    for (int i = 0; i < 32; ++i) binPos[base + i] = excl + loc[i];
}

__global__ __launch_bounds__(256) void scatter_kernel(const int* __restrict__ coords,
                                                      int* __restrict__ binPos,
                                                      int* __restrict__ perm) {
    int gid = blockIdx.x * blockDim.x + threadIdx.x;
    if (gid >= TOTAL) return;
    const int y = coords[gid * 3 + 1];
    const int x = coords[gid * 3 + 2];
    const int b = (gid >= NPTS) ? 1 : 0;
    const int key = (b << 14) | (y << 5) | (x >> 4);
    const int pos = atomicAdd(&binPos[key], 1);
    perm[pos] = gid;
}

// ---------- fused gather + MLP: 2 threads per point (before/after halves) ----------

#define LOADCH(buf, cbase)                                             \
    _Pragma("unroll")                                                  \
    for (int j = 0; j < 16; ++j) buf[j] = img_ptr[(long)((cbase) + j) * IMHW];

#define FMACH(buf, cbase)                                              \
    _Pragma("unroll")                                                  \
    for (int j = 0; j < 16; ++j) {                                     \
        const float* wr = w1b + ((cbase) + j) * HID;                   \
        _Pragma("unroll")                                              \
        for (int h = 0; h < HID; ++h) acc[h] = fmaf(buf[j], wr[h], acc[h]); \
    }

__global__ __launch_bounds__(256) void ffd_kernel(
    const float* __restrict__ before,
    const float* __restrict__ after,
    const float* __restrict__ offsets,
    const int*   __restrict__ coords,
    const float* __restrict__ W1,   // [131, 32]
    const float* __restrict__ b1,   // [32]
    const float* __restrict__ W2,   // [32, 3]
    const float* __restrict__ b2,   // [3]
    const int*   __restrict__ perm, // sorted point order (or null)
    float*       __restrict__ out)  // [2, 150000, 3]
{
    __shared__ float xch[HID][128];

    const int lp  = threadIdx.x & 127;                                  // point slot in block
    const int img = __builtin_amdgcn_readfirstlane(threadIdx.x >> 7);   // 0=before,1=after (wave-uniform)
    const int gpt = blockIdx.x * 128 + lp;
    const bool valid = gpt < TOTAL;

    int pid = 0;
    if (valid) pid = perm ? perm[gpt] : gpt;

    const long pbase = (long)pid * 3;
    int y = 0, x = 0;
    if (valid) { y = coords[pbase + 1]; x = coords[pbase + 2]; }
    const int b = (pid >= NPTS) ? 1 : 0;

    const float* img_ptr = (img ? after : before) +
                           (long)b * NCH * IMHW + (long)y * IMW + x;
    const float* w1b = W1 + img * 64 * HID;   // SGPR pointer (img uniform)

    float acc[HID];
    if (img == 0) {
        float o0 = 0.f, o1 = 0.f, o2 = 0.f;
        if (valid) { o0 = offsets[pbase]; o1 = offsets[pbase + 1]; o2 = offsets[pbase + 2]; }
        const float* r0 = W1 + 128 * HID;
        const float* r1 = W1 + 129 * HID;
        const float* r2 = W1 + 130 * HID;
        #pragma unroll
        for (int h = 0; h < HID; ++h)
            acc[h] = fmaf(o2, r2[h], fmaf(o1, r1[h], fmaf(o0, r0[h], b1[h])));
    } else {
        #pragma unroll
        for (int h = 0; h < HID; ++h) acc[h] = 0.f;
    }

    if (valid) {
        float g0[16], g1[16];
        LOADCH(g0, 0)
        LOADCH(g1, 16)
        FMACH(g0, 0)          // while g1 chunk in flight
        LOADCH(g0, 32)
        FMACH(g1, 16)
        LOADCH(g1, 48)
        FMACH(g0, 32)
        FMACH(g1, 48)
    }

    // combine halves: after-threads publish, before-threads sum + finish
    if (img == 1) {
        #pragma unroll
        for (int h = 0; h < HID; ++h) xch[h][lp] = acc[h];
    }
    __syncthreads();
    if (img == 0 && valid) {
        #pragma unroll
        for (int h = 0; h < HID; ++h) acc[h] += xch[h][lp];

        #pragma unroll
        for (int h = 0; h < HID; ++h) {
            const float xh = acc[h];
            acc[h] = 0.5f * xh * (1.0f + erff(xh * 0.70710678118654752f));
        }

        float o0 = b2[0], o1 = b2[1], o2 = b2[2];
        #pragma unroll
        for (int h = 0; h < HID; ++h) {
            o0 = fmaf(acc[h], W2[h * 3 + 0], o0);
            o1 = fmaf(acc[h], W2[h * 3 + 1], o1);
            o2 = fmaf(acc[h], W2[h * 3 + 2], o2);
        }
        out[pbase + 0] = o0;
        out[pbase + 1] = o1;
        out[pbase + 2] = o2;
    }
}

extern "C" void kernel_launch(void* const* d_in, const int* in_sizes, int n_in,
                              void* d_out, int out_size, void* d_ws, size_t ws_size,
                              hipStream_t stream) {
    const float* before  = (const float*)d_in[0];
    const float* after   = (const float*)d_in[1];
    const float* offsets = (const float*)d_in[2];
    const int*   coords  = (const int*)  d_in[3];
    const float* W1      = (const float*)d_in[4];
    const float* b1      = (const float*)d_in[5];
    const float* W2      = (const float*)d_in[6];
    const float* b2      = (const float*)d_in[7];
    float* out = (float*)d_out;

    const int block = 256;
    const int sgrid = (TOTAL + block - 1) / block;
    const int fgrid = (TOTAL + 127) / 128;   // 2 threads per point

    // ws layout: hist[NBINS] | binPos[NBINS] | perm[TOTAL]
    const size_t need = (size_t)(2 * NBINS + TOTAL) * sizeof(int);

    if (ws_size >= need) {
        int* hist   = (int*)d_ws;
        int* binPos = hist + NBINS;
        int* perm   = binPos + NBINS;

        hipMemsetAsync(hist, 0, NBINS * sizeof(int), stream);
        hist_kernel<<<sgrid, block, 0, stream>>>(coords, hist);
        scan_kernel<<<1, 1024, 0, stream>>>(hist, binPos);
        scatter_kernel<<<sgrid, block, 0, stream>>>(coords, binPos, perm);
        ffd_kernel<<<fgrid, block, 0, stream>>>(before, after, offsets, coords,
                                                W1, b1, W2, b2, perm, out);
    } else {
        ffd_kernel<<<fgrid, block, 0, stream>>>(before, after, offsets, coords,
                                                W1, b1, W2, b2, nullptr, out);
    }
}